// Round 13
// baseline (190.161 us; speedup 1.0000x reference)
//
#include <hip/hip_runtime.h>
#include <hip/hip_bf16.h>

// CausalMultiheadSelfAttention — B=2, S=2048, D=1024, H=16, dk=64
// R13: RoPE fused into QKV epilogue via precomputed sincos LUT (512 KB,
// generated in cast_all) — no libm in the GEMM epilogue (R8's spill cause),
// rope_kernel deleted. Attention identical to R12 (K-split, static-max).

#define BATCH   2
#define SEQLEN  2048
#define DMODEL  1024
#define NHEADS  16
#define DK      64

typedef __attribute__((ext_vector_type(8))) short bf16x8;
typedef __attribute__((ext_vector_type(4))) short bf16x4;
typedef __attribute__((ext_vector_type(4))) float f32x4;

__device__ __forceinline__ void gload_lds16(const void* g, void* l) {
  __builtin_amdgcn_global_load_lds(
      (const __attribute__((address_space(1))) unsigned int*)g,
      (__attribute__((address_space(3))) unsigned int*)l, 16, 0, 0);
}

__device__ __forceinline__ float fast_exp2(float x) {
#if __has_builtin(__builtin_amdgcn_exp2f)
  return __builtin_amdgcn_exp2f(x);
#else
  return exp2f(x);
#endif
}

// ------- cast fp32 -> bf16 (blocks 0..4095) + sincos LUT gen (4096..4351) ----
__global__ __launch_bounds__(256) void cast_all(
    const float* __restrict__ x,  const float* __restrict__ wq,
    const float* __restrict__ wk, const float* __restrict__ wv,
    const float* __restrict__ wo, const int* __restrict__ pos,
    __hip_bfloat16* __restrict__ xb,  __hip_bfloat16* __restrict__ wqb,
    __hip_bfloat16* __restrict__ wkb, __hip_bfloat16* __restrict__ wvb,
    __hip_bfloat16* __restrict__ wob, float2* __restrict__ lutw) {
  if (blockIdx.x >= 4096) {
    // LUT: lutw[s*32+p] = (cos, sin)(pos[s] * 10000^(-2p/64)); 65536 entries
    int idx = ((int)blockIdx.x - 4096) * 256 + (int)threadIdx.x;
    int s = idx >> 5, p = idx & 31;
    float invf = exp2f(-13.287712379549449f * ((float)(2 * p) / 64.0f));
    float ang = (float)pos[s] * invf;
    float sn, cs;
    sincosf(ang, &sn, &cs);
    lutw[idx] = make_float2(cs, sn);
    return;
  }
  const size_t MM = (size_t)1 << 20;
  size_t i = ((size_t)blockIdx.x * 256 + threadIdx.x) * 8;
  const float* src; __hip_bfloat16* dst; size_t off = i;
  if (i < 4 * MM)      { src = x;  dst = xb; }
  else if (i < 5 * MM) { src = wq; dst = wqb; off = i - 4 * MM; }
  else if (i < 6 * MM) { src = wk; dst = wkb; off = i - 5 * MM; }
  else if (i < 7 * MM) { src = wv; dst = wvb; off = i - 6 * MM; }
  else                 { src = wo; dst = wob; off = i - 7 * MM; }
  float4 a = *(const float4*)(src + off);
  float4 b = *(const float4*)(src + off + 4);
  __hip_bfloat16 t[8];
  t[0] = __float2bfloat16(a.x); t[1] = __float2bfloat16(a.y);
  t[2] = __float2bfloat16(a.z); t[3] = __float2bfloat16(a.w);
  t[4] = __float2bfloat16(b.x); t[5] = __float2bfloat16(b.y);
  t[6] = __float2bfloat16(b.z); t[7] = __float2bfloat16(b.w);
  *(bf16x8*)(dst + off) = *(const bf16x8*)t;
}

// ---------------- MFMA GEMM core: 128x128 tile, BK=32, 4 waves x 64x64 ------
__device__ __forceinline__ void gemm_core(
    const __hip_bfloat16* __restrict__ A, const __hip_bfloat16* __restrict__ W,
    int bm, int bn, int K, f32x4 (&acc)[4][4]) {
  __shared__ __hip_bfloat16 As[128 * 32];
  __shared__ __hip_bfloat16 Ws[128 * 32];
  const int tid  = threadIdx.x;
  const int wave = tid >> 6, lane = tid & 63;
  const int col  = lane & 15, quad = lane >> 4;
  const int wm   = (wave & 1) * 64, wn = (wave >> 1) * 64;
  const int srow = wave * 32;
  const int l4   = lane >> 2, sl = lane & 3;

  for (int k0 = 0; k0 < K; k0 += 32) {
#pragma unroll
    for (int c = 0; c < 2; ++c) {
      int r = srow + c * 16 + l4;
      int g = sl ^ (r & 3);
      gload_lds16(A + (size_t)(bm + r) * K + k0 + g * 8, &As[(srow + c * 16) * 32]);
      gload_lds16(W + (size_t)(bn + r) * K + k0 + g * 8, &Ws[(srow + c * 16) * 32]);
    }
    __syncthreads();
    bf16x8 af[4], bfr[4];
#pragma unroll
    for (int mt = 0; mt < 4; ++mt) {
      int r = wm + mt * 16 + col;
      af[mt] = *(const bf16x8*)&As[r * 32 + ((quad ^ (r & 3)) * 8)];
    }
#pragma unroll
    for (int nt = 0; nt < 4; ++nt) {
      int r = wn + nt * 16 + col;
      bfr[nt] = *(const bf16x8*)&Ws[r * 32 + ((quad ^ (r & 3)) * 8)];
    }
#pragma unroll
    for (int mt = 0; mt < 4; ++mt)
#pragma unroll
      for (int nt = 0; nt < 4; ++nt)
        acc[mt][nt] = __builtin_amdgcn_mfma_f32_16x16x32_bf16(af[mt], bfr[nt], acc[mt][nt], 0, 0, 0);
    __syncthreads();
  }
}

// -------- fused QKV GEMM + LUT-RoPE epilogue (z: 0=Q, 1=K, 2=V^T) ------------
__global__ __launch_bounds__(256) void mfma_qkv(
    const __hip_bfloat16* __restrict__ xb,
    const __hip_bfloat16* __restrict__ wqb,
    const __hip_bfloat16* __restrict__ wkb,
    const __hip_bfloat16* __restrict__ wvb,
    const float2* __restrict__ lut,
    __hip_bfloat16* __restrict__ Qw,
    __hip_bfloat16* __restrict__ Kw,
    __hip_bfloat16* __restrict__ Vtw) {
  const int z = blockIdx.z;
  const __hip_bfloat16* W = (z == 0) ? wqb : (z == 1) ? wkb : wvb;
  const int bm = blockIdx.x * 128, bn = blockIdx.y * 128;
  f32x4 acc[4][4] = {};
  gemm_core(xb, W, bm, bn, DMODEL, acc);

  const int wave = threadIdx.x >> 6, lane = threadIdx.x & 63;
  const int col  = lane & 15, quad = lane >> 4;
  const int wm   = (wave & 1) * 64, wn = (wave >> 1) * 64;

  if (z < 2) {
    // RoPE via LUT: feature parity == col parity; partner via shfl_xor 1.
    __hip_bfloat16* C = (z == 0) ? Qw : Kw;
    const float scl = (z == 0) ? 0.18033688011112042f : 1.0f;  // 0.125*log2(e) on Q
    const bool odd = col & 1;
#pragma unroll
    for (int mt = 0; mt < 4; ++mt)
#pragma unroll
      for (int nt = 0; nt < 4; ++nt) {
        int n = bn + wn + nt * 16 + col;
        int p = (nt * 16 + col) >> 1;             // freq index within head
#pragma unroll
        for (int r = 0; r < 4; ++r) {
          int m = bm + wm + mt * 16 + quad * 4 + r;
          float2 cs = lut[(m & (SEQLEN - 1)) * 32 + p];
          float v  = acc[mt][nt][r];
          float pv = __shfl_xor(v, 1, 64);
          float res = odd ? (v * cs.x + pv * cs.y) : (v * cs.x - pv * cs.y);
          C[(size_t)m * DMODEL + n] = __float2bfloat16(res * scl);
        }
      }
  } else {
#pragma unroll
    for (int mt = 0; mt < 4; ++mt)
#pragma unroll
      for (int nt = 0; nt < 4; ++nt) {
        int n  = bn + wn + nt * 16 + col;          // h = n>>6, dk = n&63
        int m0 = bm + wm + mt * 16 + quad * 4;     // b = m0>>11, s = m0&2047
        __hip_bfloat16 t[4];
#pragma unroll
        for (int r = 0; r < 4; ++r) t[r] = __float2bfloat16(acc[mt][nt][r]);
        size_t off = (((size_t)(m0 >> 11) * NHEADS + (n >> 6)) * DK + (n & 63)) * SEQLEN + (m0 & 2047);
        *(bf16x4*)(Vtw + off) = *(const bf16x4*)t;
      }
  }
}

// ---------------- out-projection GEMM: fp32 store to d_out -------------------
__global__ __launch_bounds__(256) void mfma_out(
    const __hip_bfloat16* __restrict__ Ow,
    const __hip_bfloat16* __restrict__ wob,
    float* __restrict__ out) {
  const int bm = blockIdx.x * 128, bn = blockIdx.y * 128;
  f32x4 acc[4][4] = {};
  gemm_core(Ow, wob, bm, bn, DMODEL, acc);
  const int wave = threadIdx.x >> 6, lane = threadIdx.x & 63;
  const int col  = lane & 15, quad = lane >> 4;
  const int wm   = (wave & 1) * 64, wn = (wave >> 1) * 64;
#pragma unroll
  for (int mt = 0; mt < 4; ++mt)
#pragma unroll
    for (int nt = 0; nt < 4; ++nt) {
      int n = bn + wn + nt * 16 + col;
#pragma unroll
      for (int r = 0; r < 4; ++r) {
        int m = bm + wm + mt * 16 + quad * 4 + r;
        out[(size_t)m * DMODEL + n] = acc[mt][nt][r];
      }
    }
}

// ---------------- K-split staged MFMA flash attention (R12) ------------------
__global__ __launch_bounds__(512) void attn_mfma(
    const __hip_bfloat16* __restrict__ Q,
    const __hip_bfloat16* __restrict__ K,
    const __hip_bfloat16* __restrict__ Vt,
    __hip_bfloat16* __restrict__ O) {
  __shared__ __align__(16) __hip_bfloat16 Ks[2][64 * 64];   // 16 KB
  __shared__ __align__(16) __hip_bfloat16 Vs[2][64 * 64];   // 16 KB
  __shared__ __align__(16) __hip_bfloat16 Pl[8][32 * 64];   // 32 KB (+fp32 scratch)
  const int lin  = (int)blockIdx.y * (int)gridDim.x + (int)blockIdx.x;  // 0..511
  const int xcd  = lin & 7, slot = lin >> 3;
  const int bh   = xcd * 4 + (slot & 3);
  const int strip = 15 - (slot >> 2);       // heavy blocks dispatched first
  const int b = bh >> 4, h = bh & 15;
  const int wave = threadIdx.x >> 6;        // 0..7
  const int lane = threadIdx.x & 63;
  const int qg = wave & 3;                  // query group: 32 q each
  const int kg = wave >> 2;                 // key half: even/odd 64-tile
  const int col = lane & 15, quad = lane >> 4;
  const int q0w = strip * 128 + qg * 32;    // wave's first query
  const int cswz = col & 7;

  const size_t qkbase = ((size_t)b * SEQLEN) * DMODEL + (size_t)h * DK;
  const size_t vbase  = (size_t)bh * DK * SEQLEN;
  __hip_bfloat16* pl = &Pl[wave][0];

  const int sr = ((int)threadIdx.x >> 3) & 63;
  const int sl = (int)threadIdx.x & 7;
  const int sgch = sl ^ (sr & 7);           // swizzled global 16B chunk

  bf16x8 stK[2], stV[2];
  auto stage_load = [&](int p) {
    const int j0 = p * 128;
#pragma unroll
    for (int g = 0; g < 2; ++g) {
      stK[g] = *(const bf16x8*)(K + qkbase + (size_t)(j0 + g * 64 + sr) * DMODEL + sgch * 8);
      stV[g] = *(const bf16x8*)(Vt + vbase + (size_t)sr * SEQLEN + j0 + g * 64 + sgch * 8);
    }
  };
  auto stage_write = [&]() {
#pragma unroll
    for (int g = 0; g < 2; ++g) {
      *(bf16x8*)&Ks[g][sr * 64 + sl * 8] = stK[g];
      *(bf16x8*)&Vs[g][sr * 64 + sl * 8] = stV[g];
    }
  };

  bf16x8 qf[2][2];
#pragma unroll
  for (int qt = 0; qt < 2; ++qt)
#pragma unroll
    for (int kc = 0; kc < 2; ++kc)
      qf[qt][kc] = *(const bf16x8*)(Q + qkbase +
          (size_t)(q0w + qt * 16 + col) * DMODEL + kc * 32 + quad * 8);

  f32x4 acc[2][4] = {};            // O^T partial (this wave's key half)
  float l_i[2] = {0.f, 0.f};       // partial softmax denominators

  const bool skip_last = (kg == 1) && (qg < 2);  // fully-masked final tile

  stage_load(0);
  stage_write();
  __syncthreads();

  for (int p = 0; p <= strip; ++p) {
    const bool pre  = p < strip;
    const bool last = p == strip;
    if (pre) stage_load(p + 1);          // long-shadow global loads

    if (!(last && skip_last)) {
      const int kb = p * 128 + kg * 64;  // this wave's key base

      f32x4 s[2][4] = {};
#pragma unroll
      for (int kt = 0; kt < 4; ++kt) {
        const int row = kt * 16 + col;
#pragma unroll
        for (int kc = 0; kc < 2; ++kc) {
          bf16x8 kf = *(const bf16x8*)&Ks[kg][row * 64 + (((kc * 4 + quad) ^ cswz) * 8)];
#pragma unroll
          for (int qt = 0; qt < 2; ++qt)
            s[qt][kt] = __builtin_amdgcn_mfma_f32_16x16x32_bf16(kf, qf[qt][kc], s[qt][kt], 0, 0, 0);
        }
      }

      if (last) {
#pragma unroll
        for (int qt = 0; qt < 2; ++qt) {
          const int q = q0w + qt * 16 + col;
#pragma unroll
          for (int kt = 0; kt < 4; ++kt)
#pragma unroll
            for (int r = 0; r < 4; ++r)
              if (kb + kt * 16 + quad * 4 + r > q) s[qt][kt][r] = -1e30f;
        }
      }

#pragma unroll
      for (int qt = 0; qt < 2; ++qt) {
#pragma unroll
        for (int kt = 0; kt < 4; ++kt) {
          __hip_bfloat16 tp[4];
#pragma unroll
          for (int r = 0; r < 4; ++r) {
            float pv = fast_exp2(s[qt][kt][r] - 24.0f);
            l_i[qt] += pv;
            tp[r] = __float2bfloat16(pv);
          }
          int c2 = ((kt << 1) | (quad >> 1)) ^ cswz;
          *(bf16x4*)(pl + (qt * 16 + col) * 64 + c2 * 8 + (quad & 1) * 4) = *(const bf16x4*)tp;
        }
      }

#pragma unroll
      for (int jc = 0; jc < 2; ++jc) {
        const int c2 = ((jc << 2) | quad) ^ cswz;
        bf16x8 pf[2];
#pragma unroll
        for (int qt = 0; qt < 2; ++qt)
          pf[qt] = *(const bf16x8*)(pl + (qt * 16 + col) * 64 + c2 * 8);
#pragma unroll
        for (int dt = 0; dt < 4; ++dt) {
          const int dv = dt * 16 + col;
          bf16x8 vf = *(const bf16x8*)&Vs[kg][dv * 64 + (((jc * 4 + quad) ^ cswz) * 8)];
#pragma unroll
          for (int qt = 0; qt < 2; ++qt)
            acc[qt][dt] = __builtin_amdgcn_mfma_f32_16x16x32_bf16(vf, pf[qt], acc[qt][dt], 0, 0, 0);
        }
      }
    }

    __syncthreads();                 // all waves done reading this pair
    if (pre) { stage_write(); __syncthreads(); }
  }

  // ---- cross-kg reduction (Pl reused as fp32 scratch), then epilogue ----
  float* accbuf = (float*)&Pl[0][0];
  float* lbuf   = (float*)&Ks[0][0];
  if (kg == 1) {
#pragma unroll
    for (int qt = 0; qt < 2; ++qt)
#pragma unroll
      for (int dt = 0; dt < 4; ++dt)
        *(f32x4*)(accbuf + ((qg * 8 + qt * 4 + dt) * 64 + lane) * 4) = acc[qt][dt];
    lbuf[(qg * 64 + lane) * 2 + 0] = l_i[0];
    lbuf[(qg * 64 + lane) * 2 + 1] = l_i[1];
  }
  __syncthreads();
  if (kg == 0) {
#pragma unroll
    for (int qt = 0; qt < 2; ++qt)
#pragma unroll
      for (int dt = 0; dt < 4; ++dt) {
        f32x4 o = *(const f32x4*)(accbuf + ((qg * 8 + qt * 4 + dt) * 64 + lane) * 4);
        acc[qt][dt] += o;
      }
    l_i[0] += lbuf[(qg * 64 + lane) * 2 + 0];
    l_i[1] += lbuf[(qg * 64 + lane) * 2 + 1];

#pragma unroll
    for (int qt = 0; qt < 2; ++qt) {
      float l = l_i[qt];
      l += __shfl_xor(l, 16, 64);
      l += __shfl_xor(l, 32, 64);
      const float inv = 1.f / l;
      const size_t orow = qkbase + (size_t)(q0w + qt * 16 + col) * DMODEL;
#pragma unroll
      for (int dt = 0; dt < 4; ++dt) {
        __hip_bfloat16 tp[4];
#pragma unroll
        for (int r = 0; r < 4; ++r) tp[r] = __float2bfloat16(acc[qt][dt][r] * inv);
        *(bf16x4*)(O + orow + dt * 16 + quad * 4) = *(const bf16x4*)tp;
      }
    }
  }
}

// ---------------- launch -----------------------------------------------------
extern "C" void kernel_launch(void* const* d_in, const int* in_sizes, int n_in,
                              void* d_out, int out_size, void* d_ws, size_t ws_size,
                              hipStream_t stream) {
  const float* x  = (const float*)d_in[0];
  const float* Wq = (const float*)d_in[1];
  const float* Wk = (const float*)d_in[2];
  const float* Wv = (const float*)d_in[3];
  const float* Wo = (const float*)d_in[4];
  const int* pos  = (const int*)d_in[5];
  float* out = (float*)d_out;

  const size_t NELEM = (size_t)BATCH * SEQLEN * DMODEL;  // 4 Mi
  const size_t WELEM = (size_t)DMODEL * DMODEL;          // 1 Mi
  __hip_bfloat16* xb  = (__hip_bfloat16*)d_ws;
  __hip_bfloat16* Qw  = xb + NELEM;
  __hip_bfloat16* Kw  = Qw + NELEM;
  __hip_bfloat16* Vtw = Kw + NELEM;                      // [b][h][dk][s]
  __hip_bfloat16* wqb = Vtw + NELEM;
  __hip_bfloat16* wkb = wqb + WELEM;
  __hip_bfloat16* wvb = wkb + WELEM;
  __hip_bfloat16* wob = wvb + WELEM;
  float2* lutw = (float2*)(wob + WELEM);                 // 65536 float2 = 512 KB
  __hip_bfloat16* Ow  = xb;   // alias: xb dead after QKV GEMM

  cast_all<<<4096 + 256, 256, 0, stream>>>(x, Wq, Wk, Wv, Wo, pos,
                                           xb, wqb, wkb, wvb, wob, lutw);

  mfma_qkv<<<dim3(32, 8, 3), 256, 0, stream>>>(xb, wqb, wkb, wvb, lutw, Qw, Kw, Vtw);

  attn_mfma<<<dim3(16, BATCH * NHEADS), 512, 0, stream>>>(Qw, Kw, Vtw, Ow);

  mfma_out<<<dim3(32, 8), 256, 0, stream>>>(Ow, wob, out);
}

// Round 14
// 187.491 us; speedup vs baseline: 1.0142x; 1.0142x over previous
//
#include <hip/hip_runtime.h>
#include <hip/hip_bf16.h>

// CausalMultiheadSelfAttention — B=2, S=2048, D=1024, H=16, dk=64
// R14: cast_all deleted — fp32->bf16 conversion folded into a reg-staged,
// double-buffered GEMM staging path (dtype-templated). 4 launches total.
// RoPE stays a standalone kernel (R13 showed epilogue fusion loses).
// Attention byte-identical to R12 (K-split, static-max, XCD swizzle).

#define BATCH   2
#define SEQLEN  2048
#define DMODEL  1024
#define NHEADS  16
#define DK      64

typedef __attribute__((ext_vector_type(8))) short bf16x8;
typedef __attribute__((ext_vector_type(4))) short bf16x4;
typedef __attribute__((ext_vector_type(4))) float f32x4;

__device__ __forceinline__ float fast_exp2(float x) {
#if __has_builtin(__builtin_amdgcn_exp2f)
  return __builtin_amdgcn_exp2f(x);
#else
  return exp2f(x);
#endif
}

// 8-element chunk load, converting to bf16 if the source is fp32
__device__ __forceinline__ bf16x8 load_cvt(const __hip_bfloat16* p) {
  return *(const bf16x8*)p;
}
__device__ __forceinline__ bf16x8 load_cvt(const float* p) {
  float4 a = *(const float4*)p;
  float4 b = *(const float4*)(p + 4);
  __hip_bfloat16 t[8];
  t[0] = __float2bfloat16(a.x); t[1] = __float2bfloat16(a.y);
  t[2] = __float2bfloat16(a.z); t[3] = __float2bfloat16(a.w);
  t[4] = __float2bfloat16(b.x); t[5] = __float2bfloat16(b.y);
  t[6] = __float2bfloat16(b.z); t[7] = __float2bfloat16(b.w);
  return *(const bf16x8*)t;
}

// ---- MFMA GEMM core: 128x128 tile, BK=32, reg-staged LDS double buffer ------
// LDS layout/swizzle byte-identical to the R12 global_load_lds version:
// row-major [row][32], slot sl holds global chunk sl^(r&3).
template <typename TA, typename TW>
__device__ __forceinline__ void gemm_core(
    const TA* __restrict__ A, const TW* __restrict__ W,
    int bm, int bn, int K, f32x4 (&acc)[4][4]) {
  __shared__ __hip_bfloat16 As[2][128 * 32];
  __shared__ __hip_bfloat16 Ws[2][128 * 32];
  const int tid  = threadIdx.x;
  const int wave = tid >> 6, lane = tid & 63;
  const int col  = lane & 15, quad = lane >> 4;
  const int wm   = (wave & 1) * 64, wn = (wave >> 1) * 64;
  const int srow = wave * 32;
  const int l4   = lane >> 2, sl = lane & 3;

  bf16x8 ra[2], rw[2];
  auto stage_load = [&](int k0) {
#pragma unroll
    for (int c = 0; c < 2; ++c) {
      int r = srow + c * 16 + l4;
      int g = sl ^ (r & 3);
      ra[c] = load_cvt(A + (size_t)(bm + r) * K + k0 + g * 8);
      rw[c] = load_cvt(W + (size_t)(bn + r) * K + k0 + g * 8);
    }
  };
  auto stage_write = [&](int buf) {
#pragma unroll
    for (int c = 0; c < 2; ++c) {
      int r = srow + c * 16 + l4;
      *(bf16x8*)&As[buf][r * 32 + sl * 8] = ra[c];
      *(bf16x8*)&Ws[buf][r * 32 + sl * 8] = rw[c];
    }
  };

  const int NK = K / 32;
  stage_load(0);
  stage_write(0);
  __syncthreads();

  for (int i = 0; i < NK; ++i) {
    const int buf = i & 1;
    const bool pre = (i + 1 < NK);
    if (pre) stage_load((i + 1) * 32);   // long-shadow global loads

    bf16x8 af[4], bfr[4];
#pragma unroll
    for (int mt = 0; mt < 4; ++mt) {
      int r = wm + mt * 16 + col;
      af[mt] = *(const bf16x8*)&As[buf][r * 32 + ((quad ^ (r & 3)) * 8)];
    }
#pragma unroll
    for (int nt = 0; nt < 4; ++nt) {
      int r = wn + nt * 16 + col;
      bfr[nt] = *(const bf16x8*)&Ws[buf][r * 32 + ((quad ^ (r & 3)) * 8)];
    }
#pragma unroll
    for (int mt = 0; mt < 4; ++mt)
#pragma unroll
      for (int nt = 0; nt < 4; ++nt)
        acc[mt][nt] = __builtin_amdgcn_mfma_f32_16x16x32_bf16(af[mt], bfr[nt], acc[mt][nt], 0, 0, 0);

    if (pre) stage_write(buf ^ 1);       // vmcnt wait lands here, post-shadow
    __syncthreads();
  }
}

// ---------------- fused QKV GEMM (z: 0=Q, 1=K, 2=V-transposed) ---------------
// Reads fp32 x and fp32 weights directly (conversion in staging).
__global__ __launch_bounds__(256) void mfma_qkv(
    const float* __restrict__ x,
    const float* __restrict__ wq,
    const float* __restrict__ wk,
    const float* __restrict__ wv,
    __hip_bfloat16* __restrict__ Qw,
    __hip_bfloat16* __restrict__ Kw,
    __hip_bfloat16* __restrict__ Vtw) {
  const int z = blockIdx.z;
  const float* W = (z == 0) ? wq : (z == 1) ? wk : wv;
  const int bm = blockIdx.x * 128, bn = blockIdx.y * 128;
  f32x4 acc[4][4] = {};
  gemm_core(x, W, bm, bn, DMODEL, acc);

  const int wave = threadIdx.x >> 6, lane = threadIdx.x & 63;
  const int col  = lane & 15, quad = lane >> 4;
  const int wm   = (wave & 1) * 64, wn = (wave >> 1) * 64;

  if (z < 2) {
    __hip_bfloat16* C = (z == 0) ? Qw : Kw;
#pragma unroll
    for (int mt = 0; mt < 4; ++mt)
#pragma unroll
      for (int nt = 0; nt < 4; ++nt) {
        int n = bn + wn + nt * 16 + col;
#pragma unroll
        for (int r = 0; r < 4; ++r) {
          int m = bm + wm + mt * 16 + quad * 4 + r;
          C[(size_t)m * DMODEL + n] = __float2bfloat16(acc[mt][nt][r]);
        }
      }
  } else {
#pragma unroll
    for (int mt = 0; mt < 4; ++mt)
#pragma unroll
      for (int nt = 0; nt < 4; ++nt) {
        int n  = bn + wn + nt * 16 + col;          // h = n>>6, dk = n&63
        int m0 = bm + wm + mt * 16 + quad * 4;     // b = m0>>11, s = m0&2047
        __hip_bfloat16 t[4];
#pragma unroll
        for (int r = 0; r < 4; ++r) t[r] = __float2bfloat16(acc[mt][nt][r]);
        size_t off = (((size_t)(m0 >> 11) * NHEADS + (n >> 6)) * DK + (n & 63)) * SEQLEN + (m0 & 2047);
        *(bf16x4*)(Vtw + off) = *(const bf16x4*)t;
      }
  }
}

// ---------------- out-projection GEMM: bf16 A x fp32 W -> fp32 out -----------
__global__ __launch_bounds__(256) void mfma_out(
    const __hip_bfloat16* __restrict__ Ow,
    const float* __restrict__ wo,
    float* __restrict__ out) {
  const int bm = blockIdx.x * 128, bn = blockIdx.y * 128;
  f32x4 acc[4][4] = {};
  gemm_core(Ow, wo, bm, bn, DMODEL, acc);
  const int wave = threadIdx.x >> 6, lane = threadIdx.x & 63;
  const int col  = lane & 15, quad = lane >> 4;
  const int wm   = (wave & 1) * 64, wn = (wave >> 1) * 64;
#pragma unroll
  for (int mt = 0; mt < 4; ++mt)
#pragma unroll
    for (int nt = 0; nt < 4; ++nt) {
      int n = bn + wn + nt * 16 + col;
#pragma unroll
      for (int r = 0; r < 4; ++r) {
        int m = bm + wm + mt * 16 + quad * 4 + r;
        out[(size_t)m * DMODEL + n] = acc[mt][nt][r];
      }
    }
}

// ---------------- RoPE; Q additionally scaled by 0.125*log2(e) ---------------
__global__ __launch_bounds__(256) void rope_kernel(
    __hip_bfloat16* __restrict__ Q,
    __hip_bfloat16* __restrict__ Kt,
    const int* __restrict__ pos, int npairs) {
  int idx = blockIdx.x * blockDim.x + threadIdx.x;
  if (idx >= npairs) return;
  int ip = idx & 511;
  int s  = (idx >> 9) & (SEQLEN - 1);
  int p  = ip & 31;
  float inv_freq = exp2f(-13.287712379549449f * ((float)(2 * p) / 64.0f));
  float ang = (float)pos[s] * inv_freq;
  float sn, cs;
  sincosf(ang, &sn, &cs);
  const float SCL = 0.18033688011112042f;  // 0.125 * log2(e)
  size_t off = (size_t)idx * 2;
  float qe = __bfloat162float(Q[off]), qo = __bfloat162float(Q[off + 1]);
  Q[off]     = __float2bfloat16((qe * cs - qo * sn) * SCL);
  Q[off + 1] = __float2bfloat16((qo * cs + qe * sn) * SCL);
  float ke = __bfloat162float(Kt[off]), ko = __bfloat162float(Kt[off + 1]);
  Kt[off]     = __float2bfloat16(ke * cs - ko * sn);
  Kt[off + 1] = __float2bfloat16(ko * cs + ke * sn);
}

// ---------------- K-split staged MFMA flash attention (R12) ------------------
__global__ __launch_bounds__(512) void attn_mfma(
    const __hip_bfloat16* __restrict__ Q,
    const __hip_bfloat16* __restrict__ K,
    const __hip_bfloat16* __restrict__ Vt,
    __hip_bfloat16* __restrict__ O) {
  __shared__ __align__(16) __hip_bfloat16 Ks[2][64 * 64];   // 16 KB
  __shared__ __align__(16) __hip_bfloat16 Vs[2][64 * 64];   // 16 KB
  __shared__ __align__(16) __hip_bfloat16 Pl[8][32 * 64];   // 32 KB (+fp32 scratch)
  const int lin  = (int)blockIdx.y * (int)gridDim.x + (int)blockIdx.x;  // 0..511
  const int xcd  = lin & 7, slot = lin >> 3;
  const int bh   = xcd * 4 + (slot & 3);
  const int strip = 15 - (slot >> 2);       // heavy blocks dispatched first
  const int b = bh >> 4, h = bh & 15;
  const int wave = threadIdx.x >> 6;        // 0..7
  const int lane = threadIdx.x & 63;
  const int qg = wave & 3;                  // query group: 32 q each
  const int kg = wave >> 2;                 // key half: even/odd 64-tile
  const int col = lane & 15, quad = lane >> 4;
  const int q0w = strip * 128 + qg * 32;    // wave's first query
  const int cswz = col & 7;

  const size_t qkbase = ((size_t)b * SEQLEN) * DMODEL + (size_t)h * DK;
  const size_t vbase  = (size_t)bh * DK * SEQLEN;
  __hip_bfloat16* pl = &Pl[wave][0];

  const int sr = ((int)threadIdx.x >> 3) & 63;
  const int sl = (int)threadIdx.x & 7;
  const int sgch = sl ^ (sr & 7);           // swizzled global 16B chunk

  bf16x8 stK[2], stV[2];
  auto stage_load = [&](int p) {
    const int j0 = p * 128;
#pragma unroll
    for (int g = 0; g < 2; ++g) {
      stK[g] = *(const bf16x8*)(K + qkbase + (size_t)(j0 + g * 64 + sr) * DMODEL + sgch * 8);
      stV[g] = *(const bf16x8*)(Vt + vbase + (size_t)sr * SEQLEN + j0 + g * 64 + sgch * 8);
    }
  };
  auto stage_write = [&]() {
#pragma unroll
    for (int g = 0; g < 2; ++g) {
      *(bf16x8*)&Ks[g][sr * 64 + sl * 8] = stK[g];
      *(bf16x8*)&Vs[g][sr * 64 + sl * 8] = stV[g];
    }
  };

  bf16x8 qf[2][2];
#pragma unroll
  for (int qt = 0; qt < 2; ++qt)
#pragma unroll
    for (int kc = 0; kc < 2; ++kc)
      qf[qt][kc] = *(const bf16x8*)(Q + qkbase +
          (size_t)(q0w + qt * 16 + col) * DMODEL + kc * 32 + quad * 8);

  f32x4 acc[2][4] = {};            // O^T partial (this wave's key half)
  float l_i[2] = {0.f, 0.f};       // partial softmax denominators

  const bool skip_last = (kg == 1) && (qg < 2);  // fully-masked final tile

  stage_load(0);
  stage_write();
  __syncthreads();

  for (int p = 0; p <= strip; ++p) {
    const bool pre  = p < strip;
    const bool last = p == strip;
    if (pre) stage_load(p + 1);          // long-shadow global loads

    if (!(last && skip_last)) {
      const int kb = p * 128 + kg * 64;  // this wave's key base

      f32x4 s[2][4] = {};
#pragma unroll
      for (int kt = 0; kt < 4; ++kt) {
        const int row = kt * 16 + col;
#pragma unroll
        for (int kc = 0; kc < 2; ++kc) {
          bf16x8 kf = *(const bf16x8*)&Ks[kg][row * 64 + (((kc * 4 + quad) ^ cswz) * 8)];
#pragma unroll
          for (int qt = 0; qt < 2; ++qt)
            s[qt][kt] = __builtin_amdgcn_mfma_f32_16x16x32_bf16(kf, qf[qt][kc], s[qt][kt], 0, 0, 0);
        }
      }

      if (last) {
#pragma unroll
        for (int qt = 0; qt < 2; ++qt) {
          const int q = q0w + qt * 16 + col;
#pragma unroll
          for (int kt = 0; kt < 4; ++kt)
#pragma unroll
            for (int r = 0; r < 4; ++r)
              if (kb + kt * 16 + quad * 4 + r > q) s[qt][kt][r] = -1e30f;
        }
      }

#pragma unroll
      for (int qt = 0; qt < 2; ++qt) {
#pragma unroll
        for (int kt = 0; kt < 4; ++kt) {
          __hip_bfloat16 tp[4];
#pragma unroll
          for (int r = 0; r < 4; ++r) {
            float pv = fast_exp2(s[qt][kt][r] - 24.0f);
            l_i[qt] += pv;
            tp[r] = __float2bfloat16(pv);
          }
          int c2 = ((kt << 1) | (quad >> 1)) ^ cswz;
          *(bf16x4*)(pl + (qt * 16 + col) * 64 + c2 * 8 + (quad & 1) * 4) = *(const bf16x4*)tp;
        }
      }

#pragma unroll
      for (int jc = 0; jc < 2; ++jc) {
        const int c2 = ((jc << 2) | quad) ^ cswz;
        bf16x8 pf[2];
#pragma unroll
        for (int qt = 0; qt < 2; ++qt)
          pf[qt] = *(const bf16x8*)(pl + (qt * 16 + col) * 64 + c2 * 8);
#pragma unroll
        for (int dt = 0; dt < 4; ++dt) {
          const int dv = dt * 16 + col;
          bf16x8 vf = *(const bf16x8*)&Vs[kg][dv * 64 + (((jc * 4 + quad) ^ cswz) * 8)];
#pragma unroll
          for (int qt = 0; qt < 2; ++qt)
            acc[qt][dt] = __builtin_amdgcn_mfma_f32_16x16x32_bf16(vf, pf[qt], acc[qt][dt], 0, 0, 0);
        }
      }
    }

    __syncthreads();                 // all waves done reading this pair
    if (pre) { stage_write(); __syncthreads(); }
  }

  // ---- cross-kg reduction (Pl reused as fp32 scratch), then epilogue ----
  float* accbuf = (float*)&Pl[0][0];
  float* lbuf   = (float*)&Ks[0][0];
  if (kg == 1) {
#pragma unroll
    for (int qt = 0; qt < 2; ++qt)
#pragma unroll
      for (int dt = 0; dt < 4; ++dt)
        *(f32x4*)(accbuf + ((qg * 8 + qt * 4 + dt) * 64 + lane) * 4) = acc[qt][dt];
    lbuf[(qg * 64 + lane) * 2 + 0] = l_i[0];
    lbuf[(qg * 64 + lane) * 2 + 1] = l_i[1];
  }
  __syncthreads();
  if (kg == 0) {
#pragma unroll
    for (int qt = 0; qt < 2; ++qt)
#pragma unroll
      for (int dt = 0; dt < 4; ++dt) {
        f32x4 o = *(const f32x4*)(accbuf + ((qg * 8 + qt * 4 + dt) * 64 + lane) * 4);
        acc[qt][dt] += o;
      }
    l_i[0] += lbuf[(qg * 64 + lane) * 2 + 0];
    l_i[1] += lbuf[(qg * 64 + lane) * 2 + 1];

#pragma unroll
    for (int qt = 0; qt < 2; ++qt) {
      float l = l_i[qt];
      l += __shfl_xor(l, 16, 64);
      l += __shfl_xor(l, 32, 64);
      const float inv = 1.f / l;
      const size_t orow = qkbase + (size_t)(q0w + qt * 16 + col) * DMODEL;
#pragma unroll
      for (int dt = 0; dt < 4; ++dt) {
        __hip_bfloat16 tp[4];
#pragma unroll
        for (int r = 0; r < 4; ++r) tp[r] = __float2bfloat16(acc[qt][dt][r] * inv);
        *(bf16x4*)(O + orow + dt * 16 + quad * 4) = *(const bf16x4*)tp;
      }
    }
  }
}

// ---------------- launch -----------------------------------------------------
extern "C" void kernel_launch(void* const* d_in, const int* in_sizes, int n_in,
                              void* d_out, int out_size, void* d_ws, size_t ws_size,
                              hipStream_t stream) {
  const float* x  = (const float*)d_in[0];
  const float* Wq = (const float*)d_in[1];
  const float* Wk = (const float*)d_in[2];
  const float* Wv = (const float*)d_in[3];
  const float* Wo = (const float*)d_in[4];
  const int* pos  = (const int*)d_in[5];
  float* out = (float*)d_out;

  const size_t NELEM = (size_t)BATCH * SEQLEN * DMODEL;  // 4 Mi
  __hip_bfloat16* Qw  = (__hip_bfloat16*)d_ws;
  __hip_bfloat16* Kw  = Qw + NELEM;
  __hip_bfloat16* Vtw = Kw + NELEM;                      // [b][h][dk][s]
  __hip_bfloat16* Ow  = Vtw + NELEM;

  mfma_qkv<<<dim3(32, 8, 3), 256, 0, stream>>>(x, Wq, Wk, Wv, Qw, Kw, Vtw);

  int npairs = BATCH * SEQLEN * (DMODEL / 2);
  rope_kernel<<<(npairs + 255) / 256, 256, 0, stream>>>(Qw, Kw, pos, npairs);

  attn_mfma<<<dim3(16, BATCH * NHEADS), 512, 0, stream>>>(Qw, Kw, Vtw, Ow);

  mfma_out<<<dim3(32, 8), 256, 0, stream>>>(Ow, Wo, out);
}